// Round 6
// baseline (861.584 us; speedup 1.0000x reference)
//
#include <hip/hip_runtime.h>

#define THREADS 256
#define SCTHREADS 1024        // scatter2 block size
#define PASS_EDGES 8192       // edges sorted per pass (64 KB LDS stage)
#define EPT 8                 // edges per thread per pass
#define GSH2 12
#define GRP2 4096             // neurons per dst-group (12-bit local id)
#define NGR 256               // max dst groups (N <= 2^20)
#define TSH 13
#define TILE 8192             // neurons per src tile (32 KB LDS stage)
#define NTIL 128              // src tiles per 2^20 neurons
#define SLAB 8192             // edges per src-sorted slab
typedef unsigned int u32;
typedef unsigned short u16;
typedef unsigned long long u64;

// ---------------- common small kernels ----------------

// v[i] = x[i] for inputs else 0 ; nxt[i] = bias-init (step-0 accumulator)
__global__ void prep_kernel(const float* __restrict__ x, const float* __restrict__ bias,
                            float* __restrict__ v, float* __restrict__ nxt,
                            int N, int IN) {
    int i = blockIdx.x * THREADS + threadIdx.x;
    if (i >= N) return;
    v[i]   = (i < IN) ? x[i] : 0.0f;
    nxt[i] = (i < IN) ? 0.0f : bias[i - IN];
}

// in-place: v = isOutput ? v : tanh(v)
__global__ void finalize0_kernel(float* __restrict__ v, int N, int OUT) {
    int i = blockIdx.x * THREADS + threadIdx.x;
    if (i >= N) return;
    float val = v[i];
    v[i] = (i >= N - OUT) ? val : tanhf(val);
}

// state = f(nxt + bias) in place; nxt holds raw accumulated sums (zero-init'd)
__global__ void finalize_fast_kernel(float* __restrict__ nxt, const float* __restrict__ bias,
                                     float* __restrict__ out,   // null except last step
                                     int N, int IN, int OUT) {
    int i = blockIdx.x * THREADS + threadIdx.x;
    if (i >= N) return;
    float val = nxt[i] + (i >= IN ? bias[i - IN] : 0.0f);
    bool isOut = (i >= N - OUT);
    float a = isOut ? val : tanhf(val);
    nxt[i] = a;
    if (out != nullptr && isOut) out[i - (N - OUT)] = a;
}

// ---------------- phase 0: per-group histogram + scans ----------------

__global__ void histo2_kernel(const int* __restrict__ dst, u32* __restrict__ mc, int E) {
    __shared__ u32 h[NGR];
    for (int i = threadIdx.x; i < NGR; i += THREADS) h[i] = 0;
    __syncthreads();
    int stride = gridDim.x * THREADS;
    int E4 = E >> 2;
    for (int k = blockIdx.x * THREADS + threadIdx.x; k < E4; k += stride) {
        int4 d = ((const int4*)dst)[k];
        atomicAdd(&h[((u32)d.x) >> GSH2], 1u);
        atomicAdd(&h[((u32)d.y) >> GSH2], 1u);
        atomicAdd(&h[((u32)d.z) >> GSH2], 1u);
        atomicAdd(&h[((u32)d.w) >> GSH2], 1u);
    }
    if (blockIdx.x == 0 && threadIdx.x == 0)
        for (int e = E4 << 2; e < E; ++e) atomicAdd(&h[((u32)dst[e]) >> GSH2], 1u);
    __syncthreads();
    for (int i = threadIdx.x; i < NGR; i += THREADS) {
        u32 c = h[i];
        if (c) atomicAdd(&mc[i], c);
    }
}

// single block, NGR threads: mo/gcursor = excl scan of counts (e9 offsets),
// mrow = excl scan of per-group slab counts (+ total at mrow[NGR])
__global__ void scan2_kernel(const u32* __restrict__ mc, u32* __restrict__ mo,
                             u32* __restrict__ gcursor, u32* __restrict__ mrow) {
    __shared__ u32 s[NGR];
    const int t = threadIdx.x;
    u32 cnt = mc[t];
    s[t] = cnt;
    __syncthreads();
    for (int off = 1; off < NGR; off <<= 1) {
        u32 v = (t >= off) ? s[t - off] : 0u;
        __syncthreads();
        s[t] += v;
        __syncthreads();
    }
    u32 excl = s[t] - cnt;
    mo[t] = excl;
    gcursor[t] = excl;
    u32 rows = (cnt + SLAB - 1u) >> 13;
    __syncthreads();
    s[t] = rows;
    __syncthreads();
    for (int off = 1; off < NGR; off <<= 1) {
        u32 v = (t >= off) ? s[t - off] : 0u;
        __syncthreads();
        s[t] += v;
        __syncthreads();
    }
    mrow[t] = s[t] - rows;
    if (t == NGR - 1) mrow[NGR] = s[t];
}

// ---------------- phase 1: dst-group cursor scatter (+ fused step-0) ----------------
// Per 8192-edge pass: LDS counting-sort by 8-bit dst-group, append each group-run
// at the group's global cursor inside e9's group region. key = src20 | dstLocal12<<20.
__global__ void __launch_bounds__(SCTHREADS)
scatter2_kernel(const int* __restrict__ src, const int* __restrict__ dst,
                const float* __restrict__ w,
                const float* __restrict__ vA,   // step-0 input state
                float* __restrict__ vB,         // step-0 accumulator (bias-init)
                u32* __restrict__ gcursor, uint2* __restrict__ e9,
                int E, int IN, int NP) {
    __shared__ __align__(16) uint2 stage[PASS_EDGES];   // 64 KB
    __shared__ u32 hc[NGR];               // histogram, then rank counter
    __shared__ u32 runStart[NGR + 1];
    __shared__ u32 gpos[NGR];

    const int tid = threadIdx.x;
    for (int i = tid; i < NGR; i += SCTHREADS) hc[i] = 0;
    __syncthreads();

    for (int p = blockIdx.x; p < NP; p += gridDim.x) {
        int ps = p * PASS_EDGES;
        int pe = ps + PASS_EDGES; if (pe > E) pe = E;

        int base = ps + tid * EPT;
        u32 pk[EPT]; u32 bk[EPT]; u32 wb[EPT];
        int cnt = 0;
        if (base + EPT <= pe) {
            int4 s0 = *(const int4*)(src + base), s1 = *(const int4*)(src + base + 4);
            int4 d0 = *(const int4*)(dst + base), d1 = *(const int4*)(dst + base + 4);
            float4 w0 = *(const float4*)(w + base), w1 = *(const float4*)(w + base + 4);
            int ss[EPT] = {s0.x, s0.y, s0.z, s0.w, s1.x, s1.y, s1.z, s1.w};
            int dd[EPT] = {d0.x, d0.y, d0.z, d0.w, d1.x, d1.y, d1.z, d1.w};
            float ww[EPT] = {w0.x, w0.y, w0.z, w0.w, w1.x, w1.y, w1.z, w1.w};
            cnt = EPT;
            #pragma unroll
            for (int i = 0; i < EPT; ++i) {
                u32 d = (u32)dd[i];
                bk[i] = d >> GSH2;
                pk[i] = (u32)ss[i] | ((d & (GRP2 - 1u)) << 20);
                wb[i] = __float_as_uint(ww[i]);
                if (ss[i] < IN) atomicAdd(&vB[dd[i]], vA[ss[i]] * ww[i]);
            }
        } else {
            for (int i = 0; i < EPT; ++i) {
                int e = base + i;
                if (e < pe) {
                    int s = src[e];
                    u32 d = (u32)dst[e];
                    float wv = w[e];
                    bk[cnt] = d >> GSH2;
                    pk[cnt] = (u32)s | ((d & (GRP2 - 1u)) << 20);
                    wb[cnt] = __float_as_uint(wv);
                    if (s < IN) atomicAdd(&vB[d], vA[s] * wv);
                    ++cnt;
                }
            }
        }

        for (int i = 0; i < cnt; ++i) atomicAdd(&hc[bk[i]], 1u);
        __syncthreads();

        // single-wave shuffle scan over NGR entries (4/lane); zero hc for ranking
        if (tid < 64) {
            u32 c[4]; u32 ssum = 0;
            #pragma unroll
            for (int k = 0; k < 4; ++k) { c[k] = hc[tid * 4 + k]; ssum += c[k]; }
            u32 inc = ssum;
            #pragma unroll
            for (int off = 1; off < 64; off <<= 1) {
                u32 t2 = __shfl_up(inc, off, 64);
                if (tid >= off) inc += t2;
            }
            u32 excl = inc - ssum;
            #pragma unroll
            for (int k = 0; k < 4; ++k) {
                runStart[tid * 4 + k] = excl;
                excl += c[k];
                hc[tid * 4 + k] = 0;
            }
            if (tid == 63) runStart[NGR] = excl;
        }
        __syncthreads();

        // cursor allocation for this pass's runs
        if (tid < NGR) {
            u32 len = runStart[tid + 1] - runStart[tid];
            gpos[tid] = len ? atomicAdd(&gcursor[tid], len) : 0u;
        }
        // ranked placement into LDS
        for (int i = 0; i < cnt; ++i) {
            u32 b = bk[i];
            u32 r = atomicAdd(&hc[b], 1u);
            stage[runStart[b] + r] = make_uint2(pk[i], wb[i]);
        }
        __syncthreads();

        // copy-out: one wave per group-run, NT u64 stores to cursor positions
        {
            const int wvv = tid >> 6, lnn = tid & 63;
            const u64* st = (const u64*)stage;
            u64* e64 = (u64*)e9;
            for (int b = wvv; b < NGR; b += (SCTHREADS >> 6)) {
                u32 s0 = runStart[b], s1 = runStart[b + 1], gp = gpos[b];
                for (u32 j = s0 + lnn; j < s1; j += 64)
                    __builtin_nontemporal_store(st[j], e64 + gp + (j - s0));
            }
        }
        if (tid < NGR) hc[tid] = 0;      // rank counts -> zero for next pass
        __syncthreads();                  // protect stage/runStart/gpos/hc
    }
}

// ---------------- phase 2: in-place src-tile slab sort ----------------
// block = one 8192-edge slab of one group's region: read slab, counting-sort by
// 7-bit src tile in LDS, write back to the SAME location + u16 dir row.
// Record is rewritten: src20|dstLocal12<<20  ->  srcLocal13|dstLocal12<<13.
__global__ void __launch_bounds__(1024)
slabsort_kernel(uint2* __restrict__ e9, const u32* __restrict__ mo,
                const u32* __restrict__ mc, const u32* __restrict__ mrow,
                u16* __restrict__ dir2) {
    __shared__ __align__(16) uint2 stg[SLAB];   // 64 KB
    __shared__ u32 hist[NTIL];
    __shared__ u32 rs2[NTIL + 1];
    __shared__ int sg;

    const int tid = threadIdx.x;
    const u32 row = blockIdx.x;
    if (row >= mrow[NGR]) return;        // uniform

    if (tid == 0) {
        int lo = 0, hi = NGR;
        while (hi - lo > 1) {
            int mid = (lo + hi) >> 1;
            if (mrow[mid] <= row) lo = mid; else hi = mid;
        }
        sg = lo;
    }
    if (tid < NTIL) hist[tid] = 0;
    __syncthreads();

    const int g = sg;
    const u32 q = row - mrow[g];
    const u32 a = mo[g] + (q << 13);
    u32 m = mc[g] - (q << 13); if (m > SLAB) m = SLAB;

    // load slab to registers + histogram
    u32 kr[8], wr2[8];
    #pragma unroll
    for (int i = 0; i < 8; ++i) {
        u32 j = (u32)tid + (u32)i * 1024u;
        if (j < m) {
            u64 rv = __builtin_nontemporal_load((const u64*)e9 + a + j);
            kr[i] = (u32)rv; wr2[i] = (u32)(rv >> 32);
            atomicAdd(&hist[(kr[i] >> TSH) & (NTIL - 1u)], 1u);
        }
    }
    __syncthreads();

    // scan 128 tile counts (wave 0, 2/lane); zero hist for ranking
    if (tid < 64) {
        u32 c0 = hist[tid * 2], c1 = hist[tid * 2 + 1];
        u32 s = c0 + c1, inc = s;
        #pragma unroll
        for (int off = 1; off < 64; off <<= 1) {
            u32 t2 = __shfl_up(inc, off, 64);
            if (tid >= off) inc += t2;
        }
        u32 excl = inc - s;
        rs2[tid * 2] = excl;
        rs2[tid * 2 + 1] = excl + c0;
        hist[tid * 2] = 0; hist[tid * 2 + 1] = 0;
        if (tid == 63) rs2[NTIL] = inc;   // == m
    }
    __syncthreads();

    // ranked placement with record repack
    #pragma unroll
    for (int i = 0; i < 8; ++i) {
        u32 j = (u32)tid + (u32)i * 1024u;
        if (j < m) {
            u32 key = kr[i];
            u32 tl = (key >> TSH) & (NTIL - 1u);
            u32 rk = atomicAdd(&hist[tl], 1u);
            u32 nk = (key & 0x1FFFu) | ((key >> 20) << TSH);
            stg[rs2[tl] + rk] = make_uint2(nk, wr2[i]);
        }
    }
    __syncthreads();

    // write back in place + directory row
    {
        const u64* st = (const u64*)stg;
        u64* out = (u64*)e9 + a;
        for (u32 j = tid; j < m; j += 1024)
            __builtin_nontemporal_store(st[j], out + j);
    }
    if (tid <= NTIL)
        dir2[row * (u32)(NTIL + 1) + (u32)tid] = (u16)rs2[tid];
}

// ---------------- phase 3: consumer (per step) ----------------
// block = (dst-group g, tile-half h). Stages one 32 KB v-tile at a time;
// per edge: sequential NT e9 load + LDS v read + LDS acc atomic.
__global__ void __launch_bounds__(1024)
consume2_kernel(const uint2* __restrict__ e9, const u16* __restrict__ dir2,
                const u32* __restrict__ mo, const u32* __restrict__ mc,
                const u32* __restrict__ mrow,
                const float* __restrict__ v_in, float* __restrict__ nxt, int N) {
    __shared__ float acc[GRP2];     // 16 KB
    __shared__ float vt[TILE];      // 32 KB
    const int tid = threadIdx.x, wv = tid >> 6, ln = tid & 63;
    const int g = blockIdx.x >> 1, h = blockIdx.x & 1;

    const u32 cnt  = mc[g];
    const u32 rowb = mrow[g];
    const u32 nq   = (cnt + SLAB - 1u) >> 13;
    const u32 eb0  = mo[g];

    for (int i = tid; i < GRP2; i += 1024) acc[i] = 0.0f;

    for (int s = h * (NTIL / 2); s < (h + 1) * (NTIL / 2); ++s) {
        int vb = s << TSH;
        if (vb >= N) break;                       // uniform
        if (vb + TILE <= N) {
            for (int j = tid; j < TILE / 4; j += 1024)
                *(float4*)&vt[j * 4] = *(const float4*)(v_in + vb + j * 4);
        } else {
            for (int j = tid; j < TILE; j += 1024) {
                int idx = vb + j;
                vt[j] = (idx < N) ? v_in[idx] : 0.0f;
            }
        }
        __syncthreads();
        for (u32 q = wv; q < nq; q += 16) {
            const u16* r2 = dir2 + (rowb + q) * (u32)(NTIL + 1) + (u32)s;
            u32 a2 = r2[0], b2 = r2[1];
            const u64* basee = (const u64*)e9 + eb0 + (q << 13);
            for (u32 j = a2 + ln; j < b2; j += 64) {
                u64 pv = __builtin_nontemporal_load(basee + j);
                u32 k = (u32)pv;
                float pw = __uint_as_float((u32)(pv >> 32));
                atomicAdd(&acc[k >> TSH], vt[k & (TILE - 1u)] * pw);
            }
        }
        __syncthreads();   // vt overwritten next tile
    }

    const int nb = g << GSH2;
    for (int j = tid; j < GRP2; j += 1024) {
        int idx = nb + j;
        if (idx < N) atomicAdd(&nxt[idx], acc[j]);
    }
}

// ---------------- fallback path (atomic version) ----------------

__global__ void edge_kernel(const int* __restrict__ src, const int* __restrict__ dst,
                            const float* __restrict__ w, const float* __restrict__ v,
                            float* __restrict__ nxt, int E) {
    int k = blockIdx.x * THREADS + threadIdx.x;
    int E4 = E >> 2;
    if (k < E4) {
        int4 s = ((const int4*)src)[k];
        int4 d = ((const int4*)dst)[k];
        float4 wv = ((const float4*)w)[k];
        atomicAdd(&nxt[d.x], v[s.x] * wv.x);
        atomicAdd(&nxt[d.y], v[s.y] * wv.y);
        atomicAdd(&nxt[d.z], v[s.z] * wv.z);
        atomicAdd(&nxt[d.w], v[s.w] * wv.w);
    }
    if (k == 0) {
        for (int e = E4 << 2; e < E; ++e)
            atomicAdd(&nxt[dst[e]], v[src[e]] * w[e]);
    }
}

__global__ void finalize_kernel(float* __restrict__ nxt, float* __restrict__ v,
                                const float* __restrict__ bias, float* __restrict__ out,
                                int N, int IN, int OUT) {
    int i = blockIdx.x * THREADS + threadIdx.x;
    if (i >= N) return;
    float val = nxt[i];
    bool isOut = (i >= N - OUT);
    float a = isOut ? val : tanhf(val);
    v[i] = a;
    nxt[i] = (i < IN) ? 0.0f : bias[i - IN];
    if (out != nullptr && isOut) out[i - (N - OUT)] = a;
}

// ---------------- launch ----------------

extern "C" void kernel_launch(void* const* d_in, const int* in_sizes, int n_in,
                              void* d_out, int out_size, void* d_ws, size_t ws_size,
                              hipStream_t stream) {
    const float* x    = (const float*)d_in[0];
    const float* w    = (const float*)d_in[1];
    const float* bias = (const float*)d_in[2];
    const int* src = (const int*)d_in[3];
    const int* dst = (const int*)d_in[4];

    const int IN  = in_sizes[0];
    const int E   = in_sizes[1];
    const int N   = IN + in_sizes[2];
    const int OUT = out_size;

    const int NP = (E + PASS_EDGES - 1) / PASS_EDGES;
    const int NG = (N + GRP2 - 1) >> GSH2;
    const int NROWS = NP + NG + 4;        // upper bound on total slabs

    int nBlocks = (N + THREADS - 1) / THREADS;

    // ---- workspace layout (in-place two-level path) ----
    uint2* e9   = (uint2*)d_ws;                                          // E recs
    size_t off  = (size_t)E * 8;
    u16*   dir2 = (u16*)((char*)d_ws + off);                             // NROWS*(NTIL+1)
    off += ((size_t)NROWS * (NTIL + 1) * 2 + 15) & ~(size_t)15;
    u32*   mc   = (u32*)((char*)d_ws + off);                             // NGR
    u32*   mo   = mc + NGR;                                              // NGR
    u32*   gcur = mo + NGR;                                              // NGR
    u32*   mrow = gcur + NGR;                                            // NGR+1
    off += ((size_t)(NGR * 3 + NGR + 1) * 4 + 15) & ~(size_t)15;
    float* vA   = (float*)((char*)d_ws + off);                           // N
    float* vB   = vA + N;                                                // N
    size_t need = off + (size_t)N * 8;

    if (ws_size >= need && N <= (NGR << GSH2)) {
        hipMemsetAsync(mc, 0, NGR * sizeof(u32), stream);
        // vA = input state; vB = step-0 accumulator (bias-init)
        prep_kernel<<<nBlocks, THREADS, 0, stream>>>(x, bias, vA, vB, N, IN);
        // phase 0: group histogram + scans
        histo2_kernel<<<1024, THREADS, 0, stream>>>(dst, mc, E);
        scan2_kernel<<<1, NGR, 0, stream>>>(mc, mo, gcur, mrow);
        // phase 1: dst-group cursor scatter (+ fused sparse step-0)
        scatter2_kernel<<<512, SCTHREADS, 0, stream>>>(
            src, dst, w, vA, vB, gcur, e9, E, IN, NP);
        finalize0_kernel<<<nBlocks, THREADS, 0, stream>>>(vB, N, OUT);   // vB = state S1
        // phase 2: in-place per-slab src-tile sort + directory
        slabsort_kernel<<<NROWS, 1024, 0, stream>>>(e9, mo, mc, mrow, dir2);
        // step 1
        hipMemsetAsync(vA, 0, (size_t)N * sizeof(float), stream);
        consume2_kernel<<<NG * 2, 1024, 0, stream>>>(e9, dir2, mo, mc, mrow, vB, vA, N);
        finalize_fast_kernel<<<nBlocks, THREADS, 0, stream>>>(vA, bias, nullptr, N, IN, OUT);
        // step 2
        hipMemsetAsync(vB, 0, (size_t)N * sizeof(float), stream);
        consume2_kernel<<<NG * 2, 1024, 0, stream>>>(e9, dir2, mo, mc, mrow, vA, vB, N);
        finalize_fast_kernel<<<nBlocks, THREADS, 0, stream>>>(vB, bias, (float*)d_out, N, IN, OUT);
    } else {
        // fallback: atomic implementation
        float* v   = (float*)d_ws;
        float* nxt = v + N;
        int eBlocks = ((E >> 2) + THREADS - 1) / THREADS;
        prep_kernel<<<nBlocks, THREADS, 0, stream>>>(x, bias, v, nxt, N, IN);
        for (int step = 0; step < 3; ++step) {
            edge_kernel<<<eBlocks, THREADS, 0, stream>>>(src, dst, w, v, nxt, E);
            float* outp = (step == 2) ? (float*)d_out : nullptr;
            finalize_kernel<<<nBlocks, THREADS, 0, stream>>>(nxt, v, bias, outp, N, IN, OUT);
        }
    }
}